// Round 6
// baseline (616.928 us; speedup 1.0000x reference)
//
#include <hip/hip_runtime.h>

typedef __bf16 bf16_t;
typedef __bf16 bf16x8 __attribute__((ext_vector_type(8)));
typedef __bf16 bf16x4 __attribute__((ext_vector_type(4)));
typedef float f32x16 __attribute__((ext_vector_type(16)));

#define MB 512
#define GROWS 96      // pair rows per g-block (3 mtiles of 32); LDS 48KB -> 3 blocks/CU
#define GT_PER_B 7    // ceil(625/96)

// ============== conv (k=3,s=2,p=1) v2: thread = one output position, all 24 channels ==============
// Input staged per-ci into a small double-buffered LDS slab (BN affine of previous layer applied at
// stage time; padding stays exact 0). Weights wT[(ci*9+t)][24] are wave-uniform -> scalar loads.
// 24 fma per 1 LDS read. Fused bias+relu+write+bn-stats epilogue.
template <int CIN, int HIN, int WIN, int HOUT, int WOUT, int OHT, int BLK>
__global__ __launch_bounds__(BLK) void conv_v2(const float* __restrict__ in,
                                               const float* __restrict__ wT,
                                               const float* __restrict__ bias,
                                               const float* __restrict__ statsIn,
                                               const float* __restrict__ gIn,
                                               const float* __restrict__ bIn, float invcntIn,
                                               float* __restrict__ out,
                                               float* __restrict__ statsOut, int tilesPerImg)
{
    constexpr int IR  = 2 * OHT + 1;
    constexpr int ICW = 2 * WOUT + 1;
    constexpr int NW  = BLK / 64;
    __shared__ float slab[2][IR * ICW];
    __shared__ float aff[CIN * 2];
    __shared__ float red[NW * 48];

    int bid = blockIdx.x;
    int n = bid / tilesPerImg, tile = bid - n * tilesPerImg;
    int oh0 = tile * OHT;
    int tid = threadIdx.x;

    if (tid < CIN) {
        if (statsIn) {
            float mean = statsIn[tid * 2] * invcntIn;
            float var  = statsIn[tid * 2 + 1] * invcntIn - mean * mean;
            float s    = gIn[tid] * rsqrtf(var + 1e-5f);
            aff[tid * 2] = s;
            aff[tid * 2 + 1] = bIn[tid] - mean * s;
        } else {
            aff[tid * 2] = 1.f;
            aff[tid * 2 + 1] = 0.f;
        }
    }
    __syncthreads();

    auto stage = [&](int ci, float* buf) {
        float sc = aff[ci * 2], sh = aff[ci * 2 + 1];
        const float* src = in + ((size_t)(n * CIN + ci) * HIN) * WIN;
        for (int idx = tid; idx < IR * ICW; idx += BLK) {
            int rr = idx / ICW, cc = idx - rr * ICW;
            int ih = 2 * oh0 - 1 + rr, iw = cc - 1;
            float v = 0.f;
            if ((unsigned)ih < (unsigned)HIN && (unsigned)iw < (unsigned)WIN)
                v = fmaf(src[ih * WIN + iw], sc, sh);
            buf[idx] = v;
        }
    };

    int nvr = HOUT - oh0; if (nvr > OHT) nvr = OHT;
    int npos = nvr * WOUT;
    bool valid = tid < npos;
    int pc = valid ? tid : 0;
    int r = pc / WOUT, q = pc - r * WOUT;

    float acc[24];
#pragma unroll
    for (int c = 0; c < 24; ++c) acc[c] = 0.f;

    stage(0, slab[0]);
    __syncthreads();

#pragma unroll 1
    for (int ci = 0; ci < CIN; ++ci) {
        const float* sp = slab[ci & 1];
        if (ci + 1 < CIN) stage(ci + 1, slab[(ci + 1) & 1]);
        const float* wp = wT + ci * 9 * 24;
        float iv[9];
#pragma unroll
        for (int t = 0; t < 9; ++t)
            iv[t] = sp[(2 * r + t / 3) * ICW + 2 * q + t % 3];
#pragma unroll
        for (int t = 0; t < 9; ++t) {
#pragma unroll
            for (int c4 = 0; c4 < 6; ++c4) {
                float4 w4 = *(const float4*)(wp + t * 24 + c4 * 4);
                acc[c4 * 4 + 0] = fmaf(iv[t], w4.x, acc[c4 * 4 + 0]);
                acc[c4 * 4 + 1] = fmaf(iv[t], w4.y, acc[c4 * 4 + 1]);
                acc[c4 * 4 + 2] = fmaf(iv[t], w4.z, acc[c4 * 4 + 2]);
                acc[c4 * 4 + 3] = fmaf(iv[t], w4.w, acc[c4 * 4 + 3]);
            }
        }
        __syncthreads();
    }

    // epilogue: bias + relu, store (coalesced per channel), bn-stats
    int wv = tid >> 6, lane = tid & 63;
#pragma unroll
    for (int c = 0; c < 24; ++c) {
        float v = fmaxf(acc[c] + bias[c], 0.f);
        if (!valid) v = 0.f;
        if (valid)
            out[((size_t)(n * 24 + c) * HOUT + oh0 + r) * WOUT + q] = v;
        float s1 = v, s2 = v * v;
#pragma unroll
        for (int o = 1; o < 64; o <<= 1) {
            s1 += __shfl_xor(s1, o);
            s2 += __shfl_xor(s2, o);
        }
        if (lane == 0) { red[wv * 48 + c * 2] = s1; red[wv * 48 + c * 2 + 1] = s2; }
    }
    __syncthreads();
    if (tid < 48) {
        float t = 0.f;
#pragma unroll
        for (int w = 0; w < NW; ++w) t += red[w * 48 + tid];
        atomicAdd(&statsOut[tid], t);
    }
}

// ---------------- build bf16 features: xf26 = [BN4(conv4) 24ch, coords 2] ; qst bf16 ----------------
__global__ void build_features(const float* __restrict__ y4, const float* __restrict__ stats4,
                               const float* __restrict__ g4, const float* __restrict__ b4,
                               const float* __restrict__ qst,
                               bf16_t* __restrict__ xf26, bf16_t* __restrict__ qstb)
{
    int idx = blockIdx.x * 256 + threadIdx.x;
    if (idx < MB * 11) qstb[idx] = (bf16_t)qst[idx];
    if (idx >= MB * 25) return;
    int b = idx / 25, p = idx % 25;
    const float invcnt = 1.f / (MB * 25);
#pragma unroll
    for (int ch = 0; ch < 24; ++ch) {
        float mean = stats4[ch * 2] * invcnt;
        float var  = stats4[ch * 2 + 1] * invcnt - mean * mean;
        float s    = g4[ch] * rsqrtf(var + 1e-5f);
        float v    = s * y4[(b * 24 + ch) * 25 + p] + (b4[ch] - mean * s);
        xf26[idx * 26 + ch] = (bf16_t)v;
    }
    xf26[idx * 26 + 24] = (bf16_t)((p / 5.0f - 2.0f) * 0.5f);
    xf26[idx * 26 + 25] = (bf16_t)(((float)(p % 5) - 2.0f) * 0.5f);
}

// ------- weight prep: g-weights in MFMA-A-frag order, fp32 transposes for f-MLP, conv wT --------
__device__ __forceinline__ void frag256(int idx, const float* __restrict__ gw, bf16_t* __restrict__ Wf)
{
    int j = idx & 7, lane = (idx >> 3) & 63, ks = (idx >> 9) & 15, nt = idx >> 13;
    int n = nt * 32 + (lane & 31), k = ks * 16 + (lane >> 5) * 8 + j;
    Wf[idx] = (bf16_t)gw[n * 256 + k];
}

// total work items: 16384 + 3*65536 + 2*65536 + 648 + 3*5184 = 360,264 -> grid 1408x256 = 360,448
__global__ void prep_weights(const float* __restrict__ gw1, const float* __restrict__ gw2,
                             const float* __restrict__ gw3, const float* __restrict__ gw4,
                             const float* __restrict__ fw1, const float* __restrict__ fw2,
                             const float* __restrict__ c1w, const float* __restrict__ c2w,
                             const float* __restrict__ c3w, const float* __restrict__ c4w,
                             bf16_t* __restrict__ W1f, bf16_t* __restrict__ W2f,
                             bf16_t* __restrict__ W3f, bf16_t* __restrict__ W4f,
                             float* __restrict__ fw1T, float* __restrict__ fw2T,
                             float* __restrict__ wT1, float* __restrict__ wT2,
                             float* __restrict__ wT3, float* __restrict__ wT4)
{
    int idx = blockIdx.x * 256 + threadIdx.x;
    if (idx < 16384) {  // W1: K=64 (63 + zero pad), [8 nt][4 ks][64][8]
        int j = idx & 7, lane = (idx >> 3) & 63, ks = (idx >> 9) & 3, nt = idx >> 11;
        int n = nt * 32 + (lane & 31), k = ks * 16 + (lane >> 5) * 8 + j;
        W1f[idx] = (k < 63) ? (bf16_t)gw1[n * 63 + k] : (bf16_t)0.0f;
        return;
    }
    idx -= 16384;
    if (idx < 65536) { frag256(idx, gw2, W2f); return; }
    idx -= 65536;
    if (idx < 65536) { frag256(idx, gw3, W3f); return; }
    idx -= 65536;
    if (idx < 65536) { frag256(idx, gw4, W4f); return; }
    idx -= 65536;
    if (idx < 65536) { int k = idx >> 8, nn = idx & 255; fw1T[idx] = fw1[nn * 256 + k]; return; }
    idx -= 65536;
    if (idx < 65536) { int k = idx >> 8, nn = idx & 255; fw2T[idx] = fw2[nn * 256 + k]; return; }
    idx -= 65536;
    if (idx < 648)   { int k = idx / 24, co = idx - k * 24; wT1[idx] = c1w[co * 27 + k]; return; }
    idx -= 648;
    if (idx < 5184)  { int k = idx / 24, co = idx - k * 24; wT2[idx] = c2w[co * 216 + k]; return; }
    idx -= 5184;
    if (idx < 5184)  { int k = idx / 24, co = idx - k * 24; wT3[idx] = c3w[co * 216 + k]; return; }
    idx -= 5184;
    if (idx < 5184)  { int k = idx / 24, co = idx - k * 24; wT4[idx] = c4w[co * 216 + k]; return; }
}

// ---------------- fused g-MLP: 32x32x16 MFMA, swapped operands (A=W, B=h^T), swizzled LDS ----------------
// LDS: hs[m][256], stride 256 bf16. 16B chunk c at row m lives at chunk slot c^(m&31).
// Wave wid owns n-tiles {2*wid, 2*wid+1} x all 96 rows. W read once per block (L2-resident).
// D[n'][m]: col=lane&31 -> m ; row=(reg&3)+8*(reg>>2)+4*(lane>>5) -> n within tile.

template <int NKS>  // K/16: 4 for layer1, 16 for layers 2-4
__device__ __forceinline__ void g_layer(const bf16_t* hs, const bf16_t* __restrict__ Wf,
                                        int wid, int lane, f32x16 acc[3][2])
{
    int m31 = lane & 31, half = lane >> 5;
#pragma unroll
    for (int mt = 0; mt < 3; ++mt)
#pragma unroll
        for (int nt = 0; nt < 2; ++nt) acc[mt][nt] = (f32x16)(0.f);
#pragma unroll
    for (int ks = 0; ks < NKS; ++ks) {
        int kc = ks * 2 + half;
        bf16x8 hf[3];
#pragma unroll
        for (int mt = 0; mt < 3; ++mt) {
            int m = mt * 32 + m31;
            hf[mt] = *(const bf16x8*)(hs + m * 256 + ((kc ^ m31) << 3));
        }
        bf16x8 wf[2];
#pragma unroll
        for (int nt = 0; nt < 2; ++nt)
            wf[nt] = *(const bf16x8*)(Wf + (size_t)(((wid * 2 + nt) * NKS + ks) * 64 + lane) * 8);
#pragma unroll
        for (int nt = 0; nt < 2; ++nt)
#pragma unroll
            for (int mt = 0; mt < 3; ++mt)
                acc[mt][nt] = __builtin_amdgcn_mfma_f32_32x32x16_bf16(wf[nt], hf[mt], acc[mt][nt], 0, 0, 0);
    }
}

__device__ __forceinline__ void g_store(bf16_t* hs, const float* __restrict__ bias,
                                        int wid, int lane, f32x16 acc[3][2])
{
    int m31 = lane & 31, half = lane >> 5;
#pragma unroll
    for (int mt = 0; mt < 3; ++mt) {
        int m = mt * 32 + m31;
#pragma unroll
        for (int nt = 0; nt < 2; ++nt) {
            int nbase = (wid * 2 + nt) * 32;
#pragma unroll
            for (int g = 0; g < 4; ++g) {
                int n0 = nbase + g * 8 + half * 4;
                float4 bv = *(const float4*)(bias + n0);
                bf16x4 v;
                v[0] = (bf16_t)fmaxf(acc[mt][nt][g * 4 + 0] + bv.x, 0.f);
                v[1] = (bf16_t)fmaxf(acc[mt][nt][g * 4 + 1] + bv.y, 0.f);
                v[2] = (bf16_t)fmaxf(acc[mt][nt][g * 4 + 2] + bv.z, 0.f);
                v[3] = (bf16_t)fmaxf(acc[mt][nt][g * 4 + 3] + bv.w, 0.f);
                int chunk = n0 >> 3;  // half*4 < 8, so chunk = (nbase + g*8) >> 3
                *(bf16x4*)(hs + m * 256 + ((chunk ^ m31) << 3) + (half << 2)) = v;
            }
        }
    }
}

__global__ void __launch_bounds__(256, 3)
g_mlp(const bf16_t* __restrict__ xf26, const bf16_t* __restrict__ qstb,
      const bf16_t* __restrict__ W1f, const bf16_t* __restrict__ W2f,
      const bf16_t* __restrict__ W3f, const bf16_t* __restrict__ W4f,
      const float* __restrict__ b1, const float* __restrict__ b2,
      const float* __restrict__ b3, const float* __restrict__ b4,
      float* __restrict__ xg)
{
    __shared__ __align__(16) bf16_t hs[GROWS * 256];   // 49,152 B -> 3 blocks/CU
    int b    = blockIdx.x / GT_PER_B;
    int tile = blockIdx.x % GT_PER_B;
    int tid  = threadIdx.x;

    // stage features (64 bf16 per row -> chunks 0..7, swizzled)
    for (int i = tid; i < GROWS * 8; i += 256) {
        int m = i >> 3, c = i & 7;
        int p = tile * GROWS + m;
        bf16x8 v;
        if (p < 625) {
            int a = p / 25, cp = p - a * 25;
            const bf16_t* f1 = xf26 + (b * 25 + cp) * 26;
            const bf16_t* f2 = xf26 + (b * 25 + a) * 26;
            const bf16_t* f3 = qstb + b * 11;
#pragma unroll
            for (int j = 0; j < 8; ++j) {
                int col = c * 8 + j;
                bf16_t u = (bf16_t)0.0f;
                if (col < 26) u = f1[col];
                else if (col < 52) u = f2[col - 26];
                else if (col < 63) u = f3[col - 52];
                v[j] = u;
            }
        } else {
#pragma unroll
            for (int j = 0; j < 8; ++j) v[j] = (bf16_t)0.0f;
        }
        *(bf16x8*)(hs + m * 256 + ((c ^ (m & 31)) << 3)) = v;
    }
    __syncthreads();

    int wid = tid >> 6, lane = tid & 63;
    int m31 = lane & 31, half = lane >> 5;
    f32x16 acc[3][2];

    g_layer<4>(hs, W1f, wid, lane, acc);
    __syncthreads(); g_store(hs, b1, wid, lane, acc); __syncthreads();
    g_layer<16>(hs, W2f, wid, lane, acc);
    __syncthreads(); g_store(hs, b2, wid, lane, acc); __syncthreads();
    g_layer<16>(hs, W3f, wid, lane, acc);
    __syncthreads(); g_store(hs, b3, wid, lane, acc); __syncthreads();
    g_layer<16>(hs, W4f, wid, lane, acc);

    // epilogue: relu(acc + b4), mask invalid rows, sum over m, atomic into xg
#pragma unroll
    for (int nt = 0; nt < 2; ++nt) {
        int nbase = (wid * 2 + nt) * 32;
        float bf[16];
#pragma unroll
        for (int r = 0; r < 16; ++r)
            bf[r] = b4[nbase + (r & 3) + 8 * (r >> 2) + 4 * half];
        f32x16 t = (f32x16)(0.f);
#pragma unroll
        for (int mt = 0; mt < 3; ++mt) {
            int p = tile * GROWS + mt * 32 + m31;
            if (p < 625) {
#pragma unroll
                for (int r = 0; r < 16; ++r)
                    t[r] += fmaxf(acc[mt][nt][r] + bf[r], 0.f);
            }
        }
#pragma unroll
        for (int off = 1; off < 32; off <<= 1) {
#pragma unroll
            for (int r = 0; r < 16; ++r) t[r] += __shfl_xor(t[r], off);
        }
        if (m31 == 0) {
#pragma unroll
            for (int r = 0; r < 16; ++r) {
                int nn = nbase + (r & 3) + 8 * (r >> 2) + 4 * half;
                atomicAdd(&xg[b * 256 + nn], t[r]);
            }
        }
    }
}

// ---------------- f-MLP (fp32) + log_softmax, one block per batch element ----------------
__global__ void f_mlp(const float* __restrict__ xg, const float* __restrict__ fw1T, const float* __restrict__ fb1,
                      const float* __restrict__ fw2T, const float* __restrict__ fb2,
                      const float* __restrict__ fw3, const float* __restrict__ fb3,
                      float* __restrict__ out)
{
    __shared__ float xa[256], xb[256], lg[10];
    int b = blockIdx.x, t = threadIdx.x;
    xa[t] = xg[b * 256 + t];
    __syncthreads();
    float a = fb1[t];
    for (int k = 0; k < 256; ++k) a += fw1T[k * 256 + t] * xa[k];
    xb[t] = fmaxf(a, 0.f);
    __syncthreads();
    a = fb2[t];
    for (int k = 0; k < 256; ++k) a += fw2T[k * 256 + t] * xb[k];
    xa[t] = fmaxf(a, 0.f);
    __syncthreads();
    if (t < 10) {
        float s = fb3[t];
        for (int k = 0; k < 256; ++k) s += fw3[t * 256 + k] * xa[k];
        lg[t] = s;
    }
    __syncthreads();
    if (t == 0) {
        float m = lg[0];
        for (int i = 1; i < 10; ++i) m = fmaxf(m, lg[i]);
        float s = 0.f;
        for (int i = 0; i < 10; ++i) s += expf(lg[i] - m);
        float ls = m + logf(s);
        for (int i = 0; i < 10; ++i) out[b * 10 + i] = lg[i] - ls;
    }
}

// ---------------- launch ----------------
extern "C" void kernel_launch(void* const* d_in, const int* in_sizes, int n_in,
                              void* d_out, int out_size, void* d_ws, size_t ws_size,
                              hipStream_t stream)
{
    (void)in_sizes; (void)n_in; (void)out_size; (void)ws_size;
    const float* img  = (const float*)d_in[0];
    const float* qst  = (const float*)d_in[1];
    const float* c1w  = (const float*)d_in[2];
    const float* c1b  = (const float*)d_in[3];
    const float* bn1g = (const float*)d_in[4];
    const float* bn1b = (const float*)d_in[5];
    const float* c2w  = (const float*)d_in[6];
    const float* c2b  = (const float*)d_in[7];
    const float* bn2g = (const float*)d_in[8];
    const float* bn2b = (const float*)d_in[9];
    const float* c3w  = (const float*)d_in[10];
    const float* c3b  = (const float*)d_in[11];
    const float* bn3g = (const float*)d_in[12];
    const float* bn3b = (const float*)d_in[13];
    const float* c4w  = (const float*)d_in[14];
    const float* c4b  = (const float*)d_in[15];
    const float* bn4g = (const float*)d_in[16];
    const float* bn4b = (const float*)d_in[17];
    const float* gw1  = (const float*)d_in[18];
    const float* gb1  = (const float*)d_in[19];
    const float* gw2  = (const float*)d_in[20];
    const float* gb2  = (const float*)d_in[21];
    const float* gw3  = (const float*)d_in[22];
    const float* gb3  = (const float*)d_in[23];
    const float* gw4  = (const float*)d_in[24];
    const float* gb4  = (const float*)d_in[25];
    const float* fw1  = (const float*)d_in[26];
    const float* fb1  = (const float*)d_in[27];
    const float* fw2  = (const float*)d_in[28];
    const float* fb2  = (const float*)d_in[29];
    const float* fw3  = (const float*)d_in[30];
    const float* fb3  = (const float*)d_in[31];

    const int Y1 = 512 * 24 * 38 * 38;
    const int Y2 = 512 * 24 * 19 * 19;
    const int Y3 = 512 * 24 * 10 * 10;
    const int Y4 = 512 * 24 * 5 * 5;

    float* fp = (float*)d_ws;
    float* y1    = fp;  fp += Y1;
    float* y2    = fp;  fp += Y2;
    float* y3    = fp;  fp += Y3;
    float* y4    = fp;  fp += Y4;
    float* stats = fp;  fp += 192;       // [4 layers][24 ch][sum, sumsq]
    float* xg    = fp;  fp += 512 * 256;
    float* fw1T  = fp;  fp += 65536;
    float* fw2T  = fp;  fp += 65536;
    float* wT1   = fp;  fp += 648;       // conv weights transposed [k][24]
    float* wT2   = fp;  fp += 5184;
    float* wT3   = fp;  fp += 5184;
    float* wT4   = fp;  fp += 5184;
    bf16_t* bp   = (bf16_t*)fp;
    bf16_t* xf26 = bp;  bp += 512 * 25 * 26;
    bf16_t* qstb = bp;  bp += 512 * 11;
    bf16_t* W1f  = bp;  bp += 16384;     // g-weights in MFMA frag order
    bf16_t* W2f  = bp;  bp += 65536;
    bf16_t* W3f  = bp;  bp += 65536;
    bf16_t* W4f  = bp;  bp += 65536;

    hipMemsetAsync(stats, 0, 192 * sizeof(float), stream);
    hipMemsetAsync(xg, 0, 512 * 256 * sizeof(float), stream);

    prep_weights<<<1408, 256, 0, stream>>>(gw1, gw2, gw3, gw4, fw1, fw2, c1w, c2w, c3w, c4w,
                                           W1f, W2f, W3f, W4f, fw1T, fw2T,
                                           wT1, wT2, wT3, wT4);

    // conv1: 75x75 -> 38x38, 4 row-tiles of 10 (10,10,10,8), 384 thr (380 positions)
    conv_v2<3, 75, 75, 38, 38, 10, 384><<<512 * 4, 384, 0, stream>>>(
        img, wT1, c1b, nullptr, nullptr, nullptr, 0.f, y1, stats + 0, 4);

    // conv2: 38x38 -> 19x19, 2 row-tiles of 10 (10,9), 192 thr (190 positions)
    conv_v2<24, 38, 38, 19, 19, 10, 192><<<512 * 2, 192, 0, stream>>>(
        y1, wT2, c2b, stats + 0, bn1g, bn1b, 1.f / (512.f * 1444.f), y2, stats + 48, 2);

    // conv3: 19x19 -> 10x10, single tile, 128 thr (100 positions)
    conv_v2<24, 19, 19, 10, 10, 10, 128><<<512, 128, 0, stream>>>(
        y2, wT3, c3b, stats + 48, bn2g, bn2b, 1.f / (512.f * 361.f), y3, stats + 96, 1);

    // conv4: 10x10 -> 5x5, single tile, 64 thr (25 positions)
    conv_v2<24, 10, 10, 5, 5, 5, 64><<<512, 64, 0, stream>>>(
        y3, wT4, c4b, stats + 96, bn3g, bn3b, 1.f / (512.f * 100.f), y4, stats + 144, 1);

    build_features<<<50, 256, 0, stream>>>(y4, stats + 144, bn4g, bn4b, qst, xf26, qstb);

    g_mlp<<<512 * GT_PER_B, 256, 0, stream>>>(xf26, qstb, W1f, W2f, W3f, W4f,
                                              gb1, gb2, gb3, gb4, xg);

    f_mlp<<<512, 256, 0, stream>>>(xg, fw1T, fb1, fw2T, fb2, fw3, fb3, (float*)d_out);
}